// Round 8
// baseline (18195.355 us; speedup 1.0000x reference)
//
#include <hip/hip_runtime.h>
#include <math.h>

#define D 128
#define D2 256
#define STK 48
#define SEQ 128
#define BATCH 32
#define RDPT 12
#define NSYN 64
#define NSEM 128
#define VOC 16384
#define EPSF 1e-6f
#define GB_C 0.8f
#define CG_C 2.0f

struct RParams {
  const int* input_ids;
  const int* prev_syn;
  const int* prev_sem;
  const float* emb_mag;
  const float* emb_phase;
  const float* cell_Wr;
  const float* cell_Wi;
  const float* norm_scale;
  const float* norm_shift;
  const float* modrelu_b;
  const float* VOr;
  const float* VOi;
  const float* halt_W;
  const float* halt_b;
  const float* stk_W;
  const float* stk_b;
  const float* cb_syn;
  const float* cb_sem;
  const float* ctxsyn_W;
  const float* ctxsyn_b;
  const float* ctxsem_W;
  const float* ctxsem_b;
  const float* gate_W;
  const float* gate_b;
  const float* cbT_syn;   // [256][64]
  const float* cbT_sem;   // [256][128]
  const float* cnrm_syn;  // [64]
  const float* cnrm_sem;  // [128]
  const float* gbsig_syn; // [64][64]
  const float* gbsig_sem; // [128][128]
  float* X;
  float* lossp;
};

__device__ __forceinline__ float waveAllSum(float v) {
  #pragma unroll
  for (int m = 32; m; m >>= 1) v += __shfl_xor(v, m);
  return v;
}

// NOTE: no min-waves clamp — 8 waves/block at <=256 VGPR still gives
// 2 waves/SIMD; the former ",2" forced a 128-VGPR cap and spilled ~90
// persistent values to scratch (R7: FETCH 90MB, WRITE 52MB of spill traffic).
__global__ __launch_bounds__(512) void recur_kernel(RParams p) {
  __shared__ float4 VO4[(D / 2) * D];        // packed (r,i,r,i) pairs, 128KB
  __shared__ float partr[512], parti[512];
  __shared__ alignas(16) float xr_[D], xi_[D], cr_[D], ci_[D];
  __shared__ float rAiA[D2], marr[D];
  __shared__ alignas(16) float zfc[D2], rd_[D2];
  __shared__ alignas(16) float acc2[D2], sl2[D2];
  __shared__ float zqs[D2];
  __shared__ float sptr[STK];
  __shared__ alignas(16) float nptrs[STK], wms[STK];
  __shared__ float hW_s[D2];
  __shared__ float stW_s[D2 * 3];
  __shared__ float scal[16];
  __shared__ int icb[2];
  __shared__ int ids[SEQ];

  const int tid = threadIdx.x;
  const int b = blockIdx.x;
  const int wv = tid >> 6;
  const int l = tid & 63;
  const int j = tid & 127;
  const int kq = tid >> 7;
  const int k0 = kq * 32;

  // ---- persistent cell weights (64 VGPR)
  float cwr[32], cwi[32];
  #pragma unroll
  for (int kk = 0; kk < 32; ++kk) {
    cwr[kk] = p.cell_Wr[(size_t)(k0 + kk) * D + j];
    cwi[kk] = p.cell_Wi[(size_t)(k0 + kk) * D + j];
  }
  // ---- persistent gate weights (128 VGPR): rows kq*128..+127, column j
  float gw[128];
  #pragma unroll
  for (int kk = 0; kk < 128; ++kk)
    gw[kk] = p.gate_W[(size_t)(kq * 128 + kk) * D + j];
  // ---- VO packed pairs -> LDS
  for (int e = tid; e < (D / 2) * D; e += 512) {
    const int kp = e >> 7;
    const int jj = e & 127;
    float4 w;
    w.x = p.VOr[(size_t)(2 * kp) * D + jj];
    w.y = p.VOi[(size_t)(2 * kp) * D + jj];
    w.z = p.VOr[(size_t)(2 * kp + 1) * D + jj];
    w.w = p.VOi[(size_t)(2 * kp + 1) * D + jj];
    VO4[e] = w;
  }
  // ---- per-thread params in regs (tid<128)
  float snsR = 0.f, nshR = 0.f, smbR = 0.f, sgbR = 0.f;
  if (tid < D) {
    snsR = p.norm_scale[tid];
    nshR = p.norm_shift[tid];
    smbR = p.modrelu_b[tid];
    sgbR = p.gate_b[tid];
  }
  if (tid < D2) hW_s[tid] = p.halt_W[tid];
  for (int e = tid; e < D2 * 3; e += 512) stW_s[e] = p.stk_W[e];
  if (tid < SEQ) ids[tid] = p.input_ids[(size_t)b * SEQ + tid];
  if (tid < STK) sptr[tid] = (tid == 0) ? 1.f : 0.f;
  if (tid == 0) { icb[0] = p.prev_syn[b]; icb[1] = p.prev_sem[b]; }
  const float hb = p.halt_b[0];
  const float sb0 = p.stk_b[0], sb1 = p.stk_b[1], sb2 = p.stk_b[2];

  // stack memory in regs: (mdl = tid&255, mjh = tid>>8) rows mjh*24..+23
  float memv[24];
  #pragma unroll
  for (int q = 0; q < 24; ++q) memv[q] = 0.f;
  const int mdl = tid & 255, mjh = tid >> 8;
  float lossAcc = 0.f;
  float remv = 1.f;
  float mNxt = 0.f, pNxt = 0.f;
  __syncthreads();

  if (tid < D) {
    const int id0 = ids[0];
    mNxt = p.emb_mag[(size_t)id0 * D + tid];
    pNxt = p.emb_phase[(size_t)id0 * D + tid];
  }

  for (int t = 0; t < SEQ; ++t) {
    if (tid < D) {
      float sv, cv;
      sincosf(pNxt, &sv, &cv);
      xr_[tid] = mNxt * cv;
      xi_[tid] = mNxt * sv;
    }
    float accR = 0.f, accI = 0.f, slR = 0.f, slI = 0.f;
    if (tid < 64) remv = 1.f;
    __syncthreads();

    for (int n = 0; n < RDPT; ++n) {
      // ---- P1: cell clin partials (reg weights, float4 broadcast x)
      {
        const float4* x4r = (const float4*)(&xr_[k0]);
        const float4* x4i = (const float4*)(&xi_[k0]);
        float a0 = 0.f, a1 = 0.f, a2 = 0.f, a3 = 0.f;
        #pragma unroll
        for (int q = 0; q < 8; ++q) {
          float4 xa = x4r[q];
          float4 xb = x4i[q];
          a0 = fmaf(xa.x, cwr[q*4+0], a0); a0 = fmaf(-xb.x, cwi[q*4+0], a0);
          a1 = fmaf(xb.x, cwr[q*4+0], a1); a1 = fmaf(xa.x, cwi[q*4+0], a1);
          a2 = fmaf(xa.y, cwr[q*4+1], a2); a2 = fmaf(-xb.y, cwi[q*4+1], a2);
          a3 = fmaf(xb.y, cwr[q*4+1], a3); a3 = fmaf(xa.y, cwi[q*4+1], a3);
          a0 = fmaf(xa.z, cwr[q*4+2], a0); a0 = fmaf(-xb.z, cwi[q*4+2], a0);
          a1 = fmaf(xb.z, cwr[q*4+2], a1); a1 = fmaf(xa.z, cwi[q*4+2], a1);
          a2 = fmaf(xa.w, cwr[q*4+3], a2); a2 = fmaf(-xb.w, cwi[q*4+3], a2);
          a3 = fmaf(xb.w, cwr[q*4+3], a3); a3 = fmaf(xa.w, cwi[q*4+3], a3);
        }
        partr[tid] = a0 + a2;
        parti[tid] = a1 + a3;
      }
      __syncthreads();
      // ---- P2: combine + magnitude (128 threads)
      if (tid < D) {
        float rr = partr[tid] + partr[tid + 128] + partr[tid + 256] + partr[tid + 384];
        float ii = parti[tid] + parti[tid + 128] + parti[tid + 256] + parti[tid + 384];
        rAiA[tid] = rr;
        rAiA[tid + 128] = ii;
        marr[tid] = sqrtf(rr * rr + ii * ii) + EPSF;
      }
      __syncthreads();
      // ---- P3: mean/var (wave 0)
      if (tid < 64) {
        float m0 = marr[l], m1 = marr[l + 64];
        float mean = waveAllSum(m0 + m1) * (1.f / D);
        float d0 = m0 - mean, d1 = m1 - mean;
        float v = waveAllSum(d0 * d0 + d1 * d1);
        if (l == 0) {
          scal[1] = mean;
          scal[2] = rsqrtf(v * (1.f / (D - 1)) + EPSF);
        }
      }
      __syncthreads();
      // ---- P4: norm + modReLU (128 threads, reg params)
      if (tid < D) {
        float m = marr[tid];
        float nm = (m - scal[1]) * scal[2] * snsR + nshR;
        float r_ = nm * rAiA[tid] / m;
        float i_ = nm * rAiA[tid + 128] / m;
        float nn = sqrtf(r_ * r_ + i_ * i_) + EPSF;
        float sc = fmaxf(nn + smbR, 0.f) / nn;
        cr_[tid] = r_ * sc;
        ci_[tid] = i_ * sc;
      }
      __syncthreads();
      // ---- P5: fused v@o clin (packed VO4 from LDS)
      {
        const float4* c4r = (const float4*)(&cr_[k0]);
        const float4* c4i = (const float4*)(&ci_[k0]);
        const float4* vbase = &VO4[(size_t)(k0 >> 1) * D + j];
        float a0 = 0.f, a1 = 0.f, a2 = 0.f, a3 = 0.f;
        #pragma unroll
        for (int q = 0; q < 8; ++q) {
          float4 xa = c4r[q];
          float4 xb = c4i[q];
          float4 wA = vbase[(size_t)(2 * q) * D];
          float4 wB = vbase[(size_t)(2 * q + 1) * D];
          a0 = fmaf(xa.x, wA.x, a0); a0 = fmaf(-xb.x, wA.y, a0);
          a1 = fmaf(xb.x, wA.x, a1); a1 = fmaf(xa.x, wA.y, a1);
          a2 = fmaf(xa.y, wA.z, a2); a2 = fmaf(-xb.y, wA.w, a2);
          a3 = fmaf(xb.y, wA.z, a3); a3 = fmaf(xa.y, wA.w, a3);
          a0 = fmaf(xa.z, wB.x, a0); a0 = fmaf(-xb.z, wB.y, a0);
          a1 = fmaf(xb.z, wB.x, a1); a1 = fmaf(xa.z, wB.y, a1);
          a2 = fmaf(xa.w, wB.z, a2); a2 = fmaf(-xb.w, wB.w, a2);
          a3 = fmaf(xb.w, wB.z, a3); a3 = fmaf(xa.w, wB.w, a3);
        }
        partr[tid] = a0 + a2;
        parti[tid] = a1 + a3;
      }
      __syncthreads();
      // ---- P6: combine -> zfc (256 threads)
      if (tid < 256) {
        if (tid < 128) {
          zfc[tid] = partr[tid] + partr[tid + 128] + partr[tid + 256] + partr[tid + 384];
        } else {
          const int d = tid - 128;
          zfc[tid] = parti[d] + parti[d + 128] + parti[d + 256] + parti[d + 384];
        }
      }
      __syncthreads();
      // ---- P7: head dots in parallel (waves 0-3)
      if (tid < 256) {
        float z0 = zfc[l], z1 = zfc[l + 64], z2 = zfc[l + 128], z3 = zfc[l + 192];
        float s;
        if (wv == 0) {
          s = z0 * hW_s[l] + z1 * hW_s[l + 64] + z2 * hW_s[l + 128] + z3 * hW_s[l + 192];
        } else {
          const int c = wv - 1;
          s = z0 * stW_s[l * 3 + c] + z1 * stW_s[(l + 64) * 3 + c] +
              z2 * stW_s[(l + 128) * 3 + c] + z3 * stW_s[(l + 192) * 3 + c];
        }
        s = waveAllSum(s);
        if (l == 0) scal[4 + wv] = s;
      }
      __syncthreads();
      // ---- P8: wave0: softmax + halt + stack pointer
      if (tid < 64) {
        float halt = 1.f / (1.f + expf(-(scal[4] + hb)));
        float e0 = scal[5] + sb0, e1 = scal[6] + sb1, e2 = scal[7] + sb2;
        float mx = fmaxf(e0, fmaxf(e1, e2));
        float x0 = expf(e0 - mx), x1 = expf(e1 - mx), x2 = expf(e2 - mx);
        float sm = x0 + x1 + x2;
        float push = x0 / sm, pop = x1 / sm, noop = x2 / sm;
        float wgt = (n == RDPT - 1) ? remv : remv * halt;
        if (l == 0) scal[3] = wgt;
        remv = remv * (1.f - halt);
        float pj = 0.f, pu = 0.f, pd = 0.f;
        if (l < STK) {
          pj = sptr[l];
          pu = sptr[(l + STK - 1) % STK];
          pd = sptr[(l + 1) % STK];
        }
        float np_ = push * pu + pop * pd + noop * pj;
        float wm_ = push * pu;
        float ssum = waveAllSum((l < STK) ? np_ : 0.f);
        float inv = 1.f / (ssum + EPSF);
        if (l < STK) {
          np_ *= inv;
          nptrs[l] = np_;
          sptr[l] = np_;
          wms[l] = wm_;
        }
      }
      __syncthreads();
      // ---- P9: stack mem update + read partials (float4 broadcasts)
      {
        const float4* wm4 = (const float4*)wms;
        const float4* np4 = (const float4*)nptrs;
        float zfd = zfc[mdl];
        float accA = 0.f, accB = 0.f;
        #pragma unroll
        for (int m4 = 0; m4 < 6; ++m4) {
          float4 wmv = wm4[mjh * 6 + m4];
          float4 npv = np4[mjh * 6 + m4];
          const int base = m4 * 4;
          memv[base + 0] = wmv.x * zfd + memv[base + 0] * (1.f - wmv.x);
          accA = fmaf(memv[base + 0], npv.x, accA);
          memv[base + 1] = wmv.y * zfd + memv[base + 1] * (1.f - wmv.y);
          accB = fmaf(memv[base + 1], npv.y, accB);
          memv[base + 2] = wmv.z * zfd + memv[base + 2] * (1.f - wmv.z);
          accA = fmaf(memv[base + 2], npv.z, accA);
          memv[base + 3] = wmv.w * zfd + memv[base + 3] * (1.f - wmv.w);
          accB = fmaf(memv[base + 3], npv.w, accB);
        }
        partr[tid] = accA + accB;
      }
      __syncthreads();
      // ---- P10: rd combine
      if (tid < D2) rd_[tid] = partr[tid] + partr[tid + 256];
      __syncthreads();
      // ---- P11: gate partials (reg weights, float4 broadcast src)
      {
        const float4* src4 = (kq < 2) ? (const float4*)(&zfc[kq * 128])
                                      : (const float4*)(&rd_[(kq - 2) * 128]);
        float g0 = 0.f, g1 = 0.f, g2 = 0.f, g3 = 0.f;
        #pragma unroll
        for (int q = 0; q < 32; ++q) {
          float4 xv = src4[q];
          g0 = fmaf(xv.x, gw[q * 4 + 0], g0);
          g1 = fmaf(xv.y, gw[q * 4 + 1], g1);
          g2 = fmaf(xv.z, gw[q * 4 + 2], g2);
          g3 = fmaf(xv.w, gw[q * 4 + 3], g3);
        }
        partr[tid] = (g0 + g1) + (g2 + g3);
      }
      __syncthreads();
      // ---- P12: sigmoid gate + gated residual + reg accumulators
      if (tid < D) {
        float g = partr[tid] + partr[tid + 128] + partr[tid + 256] +
                  partr[tid + 384] + sgbR;
        g = 1.f / (1.f + expf(-g));
        float pr_ = zfc[tid], pi_ = zfc[tid + 128];
        float rr_ = rd_[tid], ri_ = rd_[tid + 128];
        float nzr = (1.f - g) * pr_ + g * pi_ + g * (rr_ - ri_);
        float nzi = (1.f - g) * pi_ - g * pr_ + g * (ri_ + rr_);
        xr_[tid] = nzr;
        xi_[tid] = nzi;
        float wgt = scal[3];
        accR += wgt * nzr;
        accI += wgt * nzi;
        slR += nzr * (1.f / RDPT);
        slI += nzi * (1.f / RDPT);
      }
      __syncthreads();
    }  // n

    // ---- emb prefetch for t+1 (overlaps VQ section)
    if (tid < D) {
      const int idn = ids[(t + 1 < SEQ) ? t + 1 : t];
      mNxt = p.emb_mag[(size_t)idn * D + tid];
      pNxt = p.emb_phase[(size_t)idn * D + tid];
    }
    // ---- flush accumulators to LDS
    if (tid < D) {
      acc2[tid] = accR; acc2[tid + 128] = accI;
      sl2[tid] = slR;  sl2[tid + 128] = slI;
    }
    __syncthreads();

    // ---- VQ syn dots: 8 chunks x 32 k (float4 broadcast src)
    {
      const int c = tid & 63, ch = tid >> 6;
      const int kb = ch * 32;
      const float* cb = p.cbT_syn + (size_t)kb * 64 + c;
      const float* cw = p.ctxsyn_W + (size_t)kb * 64 + c;
      const float4* a4 = (const float4*)(&acc2[kb]);
      float d0 = 0.f, d1 = 0.f, e0 = 0.f, e1 = 0.f;
      #pragma unroll
      for (int q = 0; q < 8; ++q) {
        float4 zv = a4[q];
        d0 = fmaf(cb[(size_t)(q * 4 + 0) * 64], zv.x, d0);
        e0 = fmaf(cw[(size_t)(q * 4 + 0) * 64], zv.x, e0);
        d1 = fmaf(cb[(size_t)(q * 4 + 1) * 64], zv.y, d1);
        e1 = fmaf(cw[(size_t)(q * 4 + 1) * 64], zv.y, e1);
        d0 = fmaf(cb[(size_t)(q * 4 + 2) * 64], zv.z, d0);
        e0 = fmaf(cw[(size_t)(q * 4 + 2) * 64], zv.z, e0);
        d1 = fmaf(cb[(size_t)(q * 4 + 3) * 64], zv.w, d1);
        e1 = fmaf(cw[(size_t)(q * 4 + 3) * 64], zv.w, e1);
      }
      partr[ch * 64 + c] = d0 + d1;
      parti[ch * 64 + c] = e0 + e1;
    }
    __syncthreads();
    // ---- VQ syn select (wave 0)
    if (tid < 64) {
      float dot = 0.f, e = p.ctxsyn_b[l];
      #pragma unroll
      for (int ch = 0; ch < 8; ++ch) {
        dot += partr[ch * 64 + l];
        e += parti[ch * 64 + l];
      }
      float d = p.cnrm_syn[l] - 2.f * dot;
      float m = e;
      #pragma unroll
      for (int mm = 32; mm; mm >>= 1) m = fmaxf(m, __shfl_xor(m, mm));
      float ex = expf(e - m);
      float s = waveAllSum(ex);
      const int pidx = icb[0];
      float score = d - p.gbsig_syn[(size_t)pidx * 64 + l] - CG_C * (ex / s);
      float bv = score; int bi = l;
      #pragma unroll
      for (int mm = 32; mm; mm >>= 1) {
        float ov = __shfl_xor(bv, mm); int oi = __shfl_xor(bi, mm);
        if (ov < bv || (ov == bv && oi < bi)) { bv = ov; bi = oi; }
      }
      if (l == 0) icb[0] = bi;
    }
    __syncthreads();
    // ---- zq_syn gather + VQ sem dots (4 chunks x 64 k)
    if (tid < D2) {
      const int idx = icb[0];
      float zqv = p.cb_syn[(size_t)idx * D2 + tid];
      float df = zqv - acc2[tid];
      lossAcc += df * df;
      zqs[tid] = zqv;
    }
    {
      const int c = tid & 127, ch = tid >> 7;
      const int kb = ch * 64;
      const float* cb = p.cbT_sem + (size_t)kb * 128 + c;
      const float* cw = p.ctxsem_W + (size_t)kb * 128 + c;
      const float4* a4 = (const float4*)(&sl2[kb]);
      float d0 = 0.f, d1 = 0.f, e0 = 0.f, e1 = 0.f;
      #pragma unroll
      for (int q = 0; q < 16; ++q) {
        float4 zv = a4[q];
        d0 = fmaf(cb[(size_t)(q * 4 + 0) * 128], zv.x, d0);
        e0 = fmaf(cw[(size_t)(q * 4 + 0) * 128], zv.x, e0);
        d1 = fmaf(cb[(size_t)(q * 4 + 1) * 128], zv.y, d1);
        e1 = fmaf(cw[(size_t)(q * 4 + 1) * 128], zv.y, e1);
        d0 = fmaf(cb[(size_t)(q * 4 + 2) * 128], zv.z, d0);
        e0 = fmaf(cw[(size_t)(q * 4 + 2) * 128], zv.z, e0);
        d1 = fmaf(cb[(size_t)(q * 4 + 3) * 128], zv.w, d1);
        e1 = fmaf(cw[(size_t)(q * 4 + 3) * 128], zv.w, e1);
      }
      partr[ch * 128 + c] = d0 + d1;
      parti[ch * 128 + c] = e0 + e1;
    }
    __syncthreads();
    // ---- VQ sem select (wave 0)
    if (tid < 64) {
      float dot0 = 0.f, e0 = p.ctxsem_b[l];
      float dot1 = 0.f, e1 = p.ctxsem_b[l + 64];
      #pragma unroll
      for (int ch = 0; ch < 4; ++ch) {
        dot0 += partr[ch * 128 + l];       e0 += parti[ch * 128 + l];
        dot1 += partr[ch * 128 + l + 64];  e1 += parti[ch * 128 + l + 64];
      }
      float d0 = p.cnrm_sem[l] - 2.f * dot0;
      float d1 = p.cnrm_sem[l + 64] - 2.f * dot1;
      float m = fmaxf(e0, e1);
      #pragma unroll
      for (int mm = 32; mm; mm >>= 1) m = fmaxf(m, __shfl_xor(m, mm));
      float x0 = expf(e0 - m), x1 = expf(e1 - m);
      float s = waveAllSum(x0 + x1);
      const int pidx = icb[1];
      float s0 = d0 - p.gbsig_sem[(size_t)pidx * 128 + l] - CG_C * (x0 / s);
      float s1 = d1 - p.gbsig_sem[(size_t)pidx * 128 + l + 64] - CG_C * (x1 / s);
      float bv = s0; int bi = l;
      if (s1 < bv) { bv = s1; bi = l + 64; }
      #pragma unroll
      for (int mm = 32; mm; mm >>= 1) {
        float ov = __shfl_xor(bv, mm); int oi = __shfl_xor(bi, mm);
        if (ov < bv || (ov == bv && oi < bi)) { bv = ov; bi = oi; }
      }
      if (l == 0) icb[1] = bi;
    }
    __syncthreads();
    // ---- zq_sem gather + loss + X write
    if (tid < D2) {
      const int idx = icb[1];
      float zqv = p.cb_sem[(size_t)idx * D2 + tid];
      float df = zqv - sl2[tid];
      lossAcc += df * df;
      p.X[(size_t)(b * SEQ + t) * D2 + tid] = 0.5f * (zqs[tid] + zqv);
    }
    __syncthreads();
  }  // t

  // ---- block loss reduction
  partr[tid] = lossAcc;
  __syncthreads();
  if (tid < 256) partr[tid] += partr[tid + 256];
  __syncthreads();
  if (tid < 128) partr[tid] += partr[tid + 128];
  __syncthreads();
  if (tid < 64) {
    float v = partr[tid] + partr[tid + 64];
    v = waveAllSum(v);
    if (tid == 0) p.lossp[b] = v;
  }
}

// VO = V (complex) @ O (complex)
__global__ __launch_bounds__(256) void voprod_kernel(const float* __restrict__ vr,
                                                     const float* __restrict__ vi,
                                                     const float* __restrict__ orr,
                                                     const float* __restrict__ oii,
                                                     float* __restrict__ VOr,
                                                     float* __restrict__ VOi) {
  __shared__ float a_r[D], a_i[D];
  const int k = blockIdx.x;
  const int tid = threadIdx.x;
  if (tid < D) { a_r[tid] = vr[k * D + tid]; a_i[tid] = vi[k * D + tid]; }
  __syncthreads();
  const int m = tid & 127;
  const int half = tid >> 7;
  float acc = 0.f;
  if (half == 0) {
    #pragma unroll 8
    for (int jj = 0; jj < D; ++jj)
      acc += a_r[jj] * orr[jj * D + m] - a_i[jj] * oii[jj * D + m];
    VOr[k * D + m] = acc;
  } else {
    #pragma unroll 8
    for (int jj = 0; jj < D; ++jj)
      acc += a_r[jj] * oii[jj * D + m] + a_i[jj] * orr[jj * D + m];
    VOi[k * D + m] = acc;
  }
}

__global__ void vqprep_kernel(const float* __restrict__ cb_syn,
                              const float* __restrict__ cb_sem,
                              const float* __restrict__ adj_syn,
                              const float* __restrict__ adj_sem,
                              float* __restrict__ cbT_syn,
                              float* __restrict__ cbT_sem,
                              float* __restrict__ cnrm_syn,
                              float* __restrict__ cnrm_sem,
                              float* __restrict__ gbsig_syn,
                              float* __restrict__ gbsig_sem) {
  const int tid = blockIdx.x * 256 + threadIdx.x;
  const int nt = gridDim.x * 256;
  for (int e = tid; e < NSYN * D2; e += nt) {
    int c = e / D2, k = e % D2;
    cbT_syn[k * NSYN + c] = cb_syn[e];
  }
  for (int e = tid; e < NSEM * D2; e += nt) {
    int c = e / D2, k = e % D2;
    cbT_sem[k * NSEM + c] = cb_sem[e];
  }
  for (int c = tid; c < NSYN; c += nt) {
    float s = 0.f;
    for (int k = 0; k < D2; ++k) { float v = cb_syn[c * D2 + k]; s += v * v; }
    cnrm_syn[c] = s;
  }
  for (int c = tid; c < NSEM; c += nt) {
    float s = 0.f;
    for (int k = 0; k < D2; ++k) { float v = cb_sem[c * D2 + k]; s += v * v; }
    cnrm_sem[c] = s;
  }
  for (int e = tid; e < NSYN * NSYN; e += nt)
    gbsig_syn[e] = GB_C / (1.f + expf(-adj_syn[e]));
  for (int e = tid; e < NSEM * NSEM; e += nt)
    gbsig_sem[e] = GB_C / (1.f + expf(-adj_sem[e]));
}

// logits = X @ dec_W + dec_b
__global__ __launch_bounds__(256) void dec_kernel(const float* __restrict__ X,
                                                  const float* __restrict__ W,
                                                  const float* __restrict__ bias,
                                                  float* __restrict__ out) {
  __shared__ float A[32][D2];
  const int tid = threadIdx.x;
  const int bx = blockIdx.x;
  const int by = blockIdx.y;
  const float* xr = X + (size_t)by * 32 * D2;
  #pragma unroll
  for (int s = 0; s < 32; ++s) A[s][tid] = xr[s * D2 + tid];
  __syncthreads();
  const int ty = tid >> 5, tx = tid & 31;
  const int col0 = bx * 128 + tx * 4;
  const int r0 = ty * 4;
  float acc[4][4];
  #pragma unroll
  for (int r = 0; r < 4; ++r) {
    acc[r][0] = 0.f; acc[r][1] = 0.f; acc[r][2] = 0.f; acc[r][3] = 0.f;
  }
  const float* wp = W + col0;
  for (int k = 0; k < D2; k += 4) {
    float4 w0 = *(const float4*)(wp + (size_t)(k + 0) * VOC);
    float4 w1 = *(const float4*)(wp + (size_t)(k + 1) * VOC);
    float4 w2 = *(const float4*)(wp + (size_t)(k + 2) * VOC);
    float4 w3 = *(const float4*)(wp + (size_t)(k + 3) * VOC);
    #pragma unroll
    for (int r = 0; r < 4; ++r) {
      float4 a = *(const float4*)&A[r0 + r][k];
      acc[r][0] += a.x * w0.x + a.y * w1.x + a.z * w2.x + a.w * w3.x;
      acc[r][1] += a.x * w0.y + a.y * w1.y + a.z * w2.y + a.w * w3.y;
      acc[r][2] += a.x * w0.z + a.y * w1.z + a.z * w2.z + a.w * w3.z;
      acc[r][3] += a.x * w0.w + a.y * w1.w + a.z * w2.w + a.w * w3.w;
    }
  }
  float4 bv = *(const float4*)(bias + col0);
  #pragma unroll
  for (int r = 0; r < 4; ++r) {
    float4 o;
    o.x = acc[r][0] + bv.x; o.y = acc[r][1] + bv.y;
    o.z = acc[r][2] + bv.z; o.w = acc[r][3] + bv.w;
    *(float4*)(out + (size_t)(by * 32 + r0 + r) * VOC + col0) = o;
  }
}

__global__ void loss_kernel(const float* __restrict__ lp, float* __restrict__ out) {
  int l = threadIdx.x;
  float v = (l < BATCH) ? lp[l] : 0.f;
  #pragma unroll
  for (int off = 32; off; off >>= 1) v += __shfl_down(v, off);
  if (l == 0) out[0] = v * (1.25f / 8192.f);
}

extern "C" void kernel_launch(void* const* d_in, const int* in_sizes, int n_in,
                              void* d_out, int out_size, void* d_ws,
                              size_t ws_size, hipStream_t stream) {
  float* ws = (float*)d_ws;
  float* X = ws;                      // 1048576
  float* lossp = X + 1048576;         // 64
  float* VOr = lossp + 64;            // 16384
  float* VOi = VOr + 16384;           // 16384
  float* cbT_syn = VOi + 16384;       // 16384
  float* cbT_sem = cbT_syn + 16384;   // 32768
  float* cnrm_syn = cbT_sem + 32768;  // 64
  float* cnrm_sem = cnrm_syn + 64;    // 128
  float* gbsig_syn = cnrm_sem + 128;  // 4096
  float* gbsig_sem = gbsig_syn + 4096;// 16384

  RParams p;
  p.input_ids  = (const int*)d_in[0];
  p.prev_syn   = (const int*)d_in[1];
  p.prev_sem   = (const int*)d_in[2];
  p.emb_mag    = (const float*)d_in[3];
  p.emb_phase  = (const float*)d_in[4];
  p.cell_Wr    = (const float*)d_in[5];
  p.cell_Wi    = (const float*)d_in[6];
  p.norm_scale = (const float*)d_in[7];
  p.norm_shift = (const float*)d_in[8];
  p.modrelu_b  = (const float*)d_in[9];
  p.VOr        = VOr;
  p.VOi        = VOi;
  p.halt_W     = (const float*)d_in[18];
  p.halt_b     = (const float*)d_in[19];
  p.stk_W      = (const float*)d_in[20];
  p.stk_b      = (const float*)d_in[21];
  p.cb_syn     = (const float*)d_in[22];
  p.cb_sem     = (const float*)d_in[23];
  p.ctxsyn_W   = (const float*)d_in[24];
  p.ctxsyn_b   = (const float*)d_in[25];
  p.ctxsem_W   = (const float*)d_in[26];
  p.ctxsem_b   = (const float*)d_in[27];
  p.gate_W     = (const float*)d_in[30];
  p.gate_b     = (const float*)d_in[31];
  const float* dec_W = (const float*)d_in[32];
  const float* dec_b = (const float*)d_in[33];
  p.cbT_syn = cbT_syn;
  p.cbT_sem = cbT_sem;
  p.cnrm_syn = cnrm_syn;
  p.cnrm_sem = cnrm_sem;
  p.gbsig_syn = gbsig_syn;
  p.gbsig_sem = gbsig_sem;
  p.X = X;
  p.lossp = lossp;

  float* out = (float*)d_out;

  voprod_kernel<<<D, 256, 0, stream>>>((const float*)d_in[14], (const float*)d_in[15],
                                       (const float*)d_in[16], (const float*)d_in[17],
                                       VOr, VOi);
  vqprep_kernel<<<64, 256, 0, stream>>>((const float*)d_in[22], (const float*)d_in[23],
                                        (const float*)d_in[28], (const float*)d_in[29],
                                        cbT_syn, cbT_sem, cnrm_syn, cnrm_sem,
                                        gbsig_syn, gbsig_sem);
  recur_kernel<<<BATCH, 512, 0, stream>>>(p);
  dec_kernel<<<dim3(VOC / 128, BATCH * SEQ / 32), 256, 0, stream>>>(X, dec_W,
                                                                    dec_b, out);
  loss_kernel<<<1, 64, 0, stream>>>(lossp, out + (size_t)BATCH * SEQ * VOC);
}

// Round 9
// 17904.701 us; speedup vs baseline: 1.0162x; 1.0162x over previous
//
#include <hip/hip_runtime.h>
#include <hip/hip_fp16.h>
#include <math.h>

#define D 128
#define D2 256
#define STK 48
#define SEQ 128
#define BATCH 32
#define RDPT 12
#define NSYN 64
#define NSEM 128
#define VOC 16384
#define EPSF 1e-6f
#define GB_C 0.8f
#define CG_C 2.0f

struct RParams {
  const int* input_ids;
  const int* prev_syn;
  const int* prev_sem;
  const float* emb_mag;
  const float* emb_phase;
  const float* cell_Wr;
  const float* cell_Wi;
  const float* norm_scale;
  const float* norm_shift;
  const float* modrelu_b;
  const float* VOr;
  const float* VOi;
  const float* halt_W;
  const float* halt_b;
  const float* stk_W;
  const float* stk_b;
  const float* cb_syn;
  const float* cb_sem;
  const float* ctxsyn_W;
  const float* ctxsyn_b;
  const float* ctxsem_W;
  const float* ctxsem_b;
  const float* gate_b;
  const __half2* gateH;   // packed f16 pairs [256][128]: rows (2r,2r+1) x col j
  const float* cbT_syn;   // [256][64]
  const float* cbT_sem;   // [256][128]
  const float* cnrm_syn;  // [64]
  const float* cnrm_sem;  // [128]
  const float* gbsig_syn; // [64][64]
  const float* gbsig_sem; // [128][128]
  float* X;
  float* lossp;
};

__device__ __forceinline__ float waveAllSum(float v) {
  #pragma unroll
  for (int m = 32; m; m >>= 1) v += __shfl_xor(v, m);
  return v;
}

// launch_bounds(512, 1): empirically (512,2) and (512) both capped VGPRs at
// 128 (R2-R8) -> ~90 regs of persistent state spilled to scratch (52MB/dispatch
// writeback). Interpreting arg2 as min-blocks/CU: 1 block * 8 waves / 4 SIMD
// = 2 waves/EU -> 256-VGPR cap, the feasible max for an 8-wave block.
__global__ __launch_bounds__(512, 1) void recur_kernel(RParams p) {
  __shared__ float4 VO4[(D / 2) * D];        // packed (r,i,r,i) pairs, 128KB
  __shared__ float partr[512], parti[512];
  __shared__ alignas(16) float xr_[D], xi_[D], cr_[D], ci_[D];
  __shared__ float rAiA[D2], marr[D];
  __shared__ alignas(16) float zfc[D2], rd_[D2];
  __shared__ alignas(16) float acc2[D2], sl2[D2];
  __shared__ float zqs[D2];
  __shared__ float sptr[STK];
  __shared__ alignas(16) float nptrs[STK], wms[STK];
  __shared__ float hW_s[D2];
  __shared__ float stW_s[D2 * 3];
  __shared__ float scal[16];
  __shared__ int icb[2];
  __shared__ int ids[SEQ];

  const int tid = threadIdx.x;
  const int b = blockIdx.x;
  const int wv = tid >> 6;
  const int l = tid & 63;
  const int j = tid & 127;
  const int kq = tid >> 7;
  const int k0 = kq * 32;

  // ---- persistent cell weights (64 VGPR)
  float cwr[32], cwi[32];
  #pragma unroll
  for (int kk = 0; kk < 32; ++kk) {
    cwr[kk] = p.cell_Wr[(size_t)(k0 + kk) * D + j];
    cwi[kk] = p.cell_Wi[(size_t)(k0 + kk) * D + j];
  }
  // ---- persistent gate weights, f16-packed (64 VGPR): row-pairs kq*64..+63
  __half2 gwh[64];
  #pragma unroll
  for (int q = 0; q < 64; ++q)
    gwh[q] = p.gateH[(size_t)(kq * 64 + q) * D + j];
  // ---- VO packed pairs -> LDS
  for (int e = tid; e < (D / 2) * D; e += 512) {
    const int kp = e >> 7;
    const int jj = e & 127;
    float4 w;
    w.x = p.VOr[(size_t)(2 * kp) * D + jj];
    w.y = p.VOi[(size_t)(2 * kp) * D + jj];
    w.z = p.VOr[(size_t)(2 * kp + 1) * D + jj];
    w.w = p.VOi[(size_t)(2 * kp + 1) * D + jj];
    VO4[e] = w;
  }
  // ---- per-thread params in regs (tid<128)
  float snsR = 0.f, nshR = 0.f, smbR = 0.f, sgbR = 0.f;
  if (tid < D) {
    snsR = p.norm_scale[tid];
    nshR = p.norm_shift[tid];
    smbR = p.modrelu_b[tid];
    sgbR = p.gate_b[tid];
  }
  if (tid < D2) hW_s[tid] = p.halt_W[tid];
  for (int e = tid; e < D2 * 3; e += 512) stW_s[e] = p.stk_W[e];
  if (tid < SEQ) ids[tid] = p.input_ids[(size_t)b * SEQ + tid];
  if (tid < STK) sptr[tid] = (tid == 0) ? 1.f : 0.f;
  if (tid == 0) { icb[0] = p.prev_syn[b]; icb[1] = p.prev_sem[b]; }
  const float hb = p.halt_b[0];
  const float sb0 = p.stk_b[0], sb1 = p.stk_b[1], sb2 = p.stk_b[2];

  // stack memory in regs: (mdl = tid&255, mjh = tid>>8) rows mjh*24..+23
  float memv[24];
  #pragma unroll
  for (int q = 0; q < 24; ++q) memv[q] = 0.f;
  const int mdl = tid & 255, mjh = tid >> 8;
  float lossAcc = 0.f;
  float remv = 1.f;
  float mNxt = 0.f, pNxt = 0.f;
  __syncthreads();

  if (tid < D) {
    const int id0 = ids[0];
    mNxt = p.emb_mag[(size_t)id0 * D + tid];
    pNxt = p.emb_phase[(size_t)id0 * D + tid];
  }

  for (int t = 0; t < SEQ; ++t) {
    if (tid < D) {
      float sv, cv;
      sincosf(pNxt, &sv, &cv);
      xr_[tid] = mNxt * cv;
      xi_[tid] = mNxt * sv;
    }
    float accR = 0.f, accI = 0.f, slR = 0.f, slI = 0.f;
    if (tid < 64) remv = 1.f;
    __syncthreads();

    for (int n = 0; n < RDPT; ++n) {
      // ---- P1: cell clin partials (reg weights, float4 broadcast x)
      {
        const float4* x4r = (const float4*)(&xr_[k0]);
        const float4* x4i = (const float4*)(&xi_[k0]);
        float a0 = 0.f, a1 = 0.f, a2 = 0.f, a3 = 0.f;
        #pragma unroll
        for (int q = 0; q < 8; ++q) {
          float4 xa = x4r[q];
          float4 xb = x4i[q];
          a0 = fmaf(xa.x, cwr[q*4+0], a0); a0 = fmaf(-xb.x, cwi[q*4+0], a0);
          a1 = fmaf(xb.x, cwr[q*4+0], a1); a1 = fmaf(xa.x, cwi[q*4+0], a1);
          a2 = fmaf(xa.y, cwr[q*4+1], a2); a2 = fmaf(-xb.y, cwi[q*4+1], a2);
          a3 = fmaf(xb.y, cwr[q*4+1], a3); a3 = fmaf(xa.y, cwi[q*4+1], a3);
          a0 = fmaf(xa.z, cwr[q*4+2], a0); a0 = fmaf(-xb.z, cwi[q*4+2], a0);
          a1 = fmaf(xb.z, cwr[q*4+2], a1); a1 = fmaf(xa.z, cwi[q*4+2], a1);
          a2 = fmaf(xa.w, cwr[q*4+3], a2); a2 = fmaf(-xb.w, cwi[q*4+3], a2);
          a3 = fmaf(xb.w, cwr[q*4+3], a3); a3 = fmaf(xa.w, cwi[q*4+3], a3);
        }
        partr[tid] = a0 + a2;
        parti[tid] = a1 + a3;
      }
      __syncthreads();
      // ---- P2: combine + magnitude (128 threads)
      if (tid < D) {
        float rr = partr[tid] + partr[tid + 128] + partr[tid + 256] + partr[tid + 384];
        float ii = parti[tid] + parti[tid + 128] + parti[tid + 256] + parti[tid + 384];
        rAiA[tid] = rr;
        rAiA[tid + 128] = ii;
        marr[tid] = sqrtf(rr * rr + ii * ii) + EPSF;
      }
      __syncthreads();
      // ---- P3: mean/var (wave 0)
      if (tid < 64) {
        float m0 = marr[l], m1 = marr[l + 64];
        float mean = waveAllSum(m0 + m1) * (1.f / D);
        float d0 = m0 - mean, d1 = m1 - mean;
        float v = waveAllSum(d0 * d0 + d1 * d1);
        if (l == 0) {
          scal[1] = mean;
          scal[2] = rsqrtf(v * (1.f / (D - 1)) + EPSF);
        }
      }
      __syncthreads();
      // ---- P4: norm + modReLU (128 threads, reg params)
      if (tid < D) {
        float m = marr[tid];
        float nm = (m - scal[1]) * scal[2] * snsR + nshR;
        float r_ = nm * rAiA[tid] / m;
        float i_ = nm * rAiA[tid + 128] / m;
        float nn = sqrtf(r_ * r_ + i_ * i_) + EPSF;
        float sc = fmaxf(nn + smbR, 0.f) / nn;
        cr_[tid] = r_ * sc;
        ci_[tid] = i_ * sc;
      }
      __syncthreads();
      // ---- P5: fused v@o clin (packed VO4 from LDS)
      {
        const float4* c4r = (const float4*)(&cr_[k0]);
        const float4* c4i = (const float4*)(&ci_[k0]);
        const float4* vbase = &VO4[(size_t)(k0 >> 1) * D + j];
        float a0 = 0.f, a1 = 0.f, a2 = 0.f, a3 = 0.f;
        #pragma unroll
        for (int q = 0; q < 8; ++q) {
          float4 xa = c4r[q];
          float4 xb = c4i[q];
          float4 wA = vbase[(size_t)(2 * q) * D];
          float4 wB = vbase[(size_t)(2 * q + 1) * D];
          a0 = fmaf(xa.x, wA.x, a0); a0 = fmaf(-xb.x, wA.y, a0);
          a1 = fmaf(xb.x, wA.x, a1); a1 = fmaf(xa.x, wA.y, a1);
          a2 = fmaf(xa.y, wA.z, a2); a2 = fmaf(-xb.y, wA.w, a2);
          a3 = fmaf(xb.y, wA.z, a3); a3 = fmaf(xa.y, wA.w, a3);
          a0 = fmaf(xa.z, wB.x, a0); a0 = fmaf(-xb.z, wB.y, a0);
          a1 = fmaf(xb.z, wB.x, a1); a1 = fmaf(xa.z, wB.y, a1);
          a2 = fmaf(xa.w, wB.z, a2); a2 = fmaf(-xb.w, wB.w, a2);
          a3 = fmaf(xb.w, wB.z, a3); a3 = fmaf(xa.w, wB.w, a3);
        }
        partr[tid] = a0 + a2;
        parti[tid] = a1 + a3;
      }
      __syncthreads();
      // ---- P6: combine -> zfc (256 threads)
      if (tid < 256) {
        if (tid < 128) {
          zfc[tid] = partr[tid] + partr[tid + 128] + partr[tid + 256] + partr[tid + 384];
        } else {
          const int d = tid - 128;
          zfc[tid] = parti[d] + parti[d + 128] + parti[d + 256] + parti[d + 384];
        }
      }
      __syncthreads();
      // ---- P7: head dots in parallel (waves 0-3)
      if (tid < 256) {
        float z0 = zfc[l], z1 = zfc[l + 64], z2 = zfc[l + 128], z3 = zfc[l + 192];
        float s;
        if (wv == 0) {
          s = z0 * hW_s[l] + z1 * hW_s[l + 64] + z2 * hW_s[l + 128] + z3 * hW_s[l + 192];
        } else {
          const int c = wv - 1;
          s = z0 * stW_s[l * 3 + c] + z1 * stW_s[(l + 64) * 3 + c] +
              z2 * stW_s[(l + 128) * 3 + c] + z3 * stW_s[(l + 192) * 3 + c];
        }
        s = waveAllSum(s);
        if (l == 0) scal[4 + wv] = s;
      }
      __syncthreads();
      // ---- P8: wave0: softmax + halt + stack pointer
      if (tid < 64) {
        float halt = 1.f / (1.f + expf(-(scal[4] + hb)));
        float e0 = scal[5] + sb0, e1 = scal[6] + sb1, e2 = scal[7] + sb2;
        float mx = fmaxf(e0, fmaxf(e1, e2));
        float x0 = expf(e0 - mx), x1 = expf(e1 - mx), x2 = expf(e2 - mx);
        float sm = x0 + x1 + x2;
        float push = x0 / sm, pop = x1 / sm, noop = x2 / sm;
        float wgt = (n == RDPT - 1) ? remv : remv * halt;
        if (l == 0) scal[3] = wgt;
        remv = remv * (1.f - halt);
        float pj = 0.f, pu = 0.f, pd = 0.f;
        if (l < STK) {
          pj = sptr[l];
          pu = sptr[(l + STK - 1) % STK];
          pd = sptr[(l + 1) % STK];
        }
        float np_ = push * pu + pop * pd + noop * pj;
        float wm_ = push * pu;
        float ssum = waveAllSum((l < STK) ? np_ : 0.f);
        float inv = 1.f / (ssum + EPSF);
        if (l < STK) {
          np_ *= inv;
          nptrs[l] = np_;
          sptr[l] = np_;
          wms[l] = wm_;
        }
      }
      __syncthreads();
      // ---- P9: stack mem update + read partials (float4 broadcasts)
      {
        const float4* wm4 = (const float4*)wms;
        const float4* np4 = (const float4*)nptrs;
        float zfd = zfc[mdl];
        float accA = 0.f, accB = 0.f;
        #pragma unroll
        for (int m4 = 0; m4 < 6; ++m4) {
          float4 wmv = wm4[mjh * 6 + m4];
          float4 npv = np4[mjh * 6 + m4];
          const int base = m4 * 4;
          memv[base + 0] = wmv.x * zfd + memv[base + 0] * (1.f - wmv.x);
          accA = fmaf(memv[base + 0], npv.x, accA);
          memv[base + 1] = wmv.y * zfd + memv[base + 1] * (1.f - wmv.y);
          accB = fmaf(memv[base + 1], npv.y, accB);
          memv[base + 2] = wmv.z * zfd + memv[base + 2] * (1.f - wmv.z);
          accA = fmaf(memv[base + 2], npv.z, accA);
          memv[base + 3] = wmv.w * zfd + memv[base + 3] * (1.f - wmv.w);
          accB = fmaf(memv[base + 3], npv.w, accB);
        }
        partr[tid] = accA + accB;
      }
      __syncthreads();
      // ---- P10: rd combine
      if (tid < D2) rd_[tid] = partr[tid] + partr[tid + 256];
      __syncthreads();
      // ---- P11: gate partials (f16-packed reg weights, float4 broadcast src)
      {
        const float4* src4 = (kq < 2) ? (const float4*)(&zfc[kq * 128])
                                      : (const float4*)(&rd_[(kq - 2) * 128]);
        float g0 = 0.f, g1 = 0.f, g2 = 0.f, g3 = 0.f;
        #pragma unroll
        for (int q = 0; q < 32; ++q) {
          float4 xv = src4[q];
          float2 wa = __half22float2(gwh[2 * q]);
          float2 wb = __half22float2(gwh[2 * q + 1]);
          g0 = fmaf(xv.x, wa.x, g0);
          g1 = fmaf(xv.y, wa.y, g1);
          g2 = fmaf(xv.z, wb.x, g2);
          g3 = fmaf(xv.w, wb.y, g3);
        }
        partr[tid] = (g0 + g1) + (g2 + g3);
      }
      __syncthreads();
      // ---- P12: sigmoid gate + gated residual + reg accumulators
      if (tid < D) {
        float g = partr[tid] + partr[tid + 128] + partr[tid + 256] +
                  partr[tid + 384] + sgbR;
        g = 1.f / (1.f + expf(-g));
        float pr_ = zfc[tid], pi_ = zfc[tid + 128];
        float rr_ = rd_[tid], ri_ = rd_[tid + 128];
        float nzr = (1.f - g) * pr_ + g * pi_ + g * (rr_ - ri_);
        float nzi = (1.f - g) * pi_ - g * pr_ + g * (ri_ + rr_);
        xr_[tid] = nzr;
        xi_[tid] = nzi;
        float wgt = scal[3];
        accR += wgt * nzr;
        accI += wgt * nzi;
        slR += nzr * (1.f / RDPT);
        slI += nzi * (1.f / RDPT);
      }
      __syncthreads();
    }  // n

    // ---- emb prefetch for t+1 (overlaps VQ section)
    if (tid < D) {
      const int idn = ids[(t + 1 < SEQ) ? t + 1 : t];
      mNxt = p.emb_mag[(size_t)idn * D + tid];
      pNxt = p.emb_phase[(size_t)idn * D + tid];
    }
    // ---- flush accumulators to LDS
    if (tid < D) {
      acc2[tid] = accR; acc2[tid + 128] = accI;
      sl2[tid] = slR;  sl2[tid + 128] = slI;
    }
    __syncthreads();

    // ---- VQ syn dots: 8 chunks x 32 k (float4 broadcast src)
    {
      const int c = tid & 63, ch = tid >> 6;
      const int kb = ch * 32;
      const float* cb = p.cbT_syn + (size_t)kb * 64 + c;
      const float* cw = p.ctxsyn_W + (size_t)kb * 64 + c;
      const float4* a4 = (const float4*)(&acc2[kb]);
      float d0 = 0.f, d1 = 0.f, e0 = 0.f, e1 = 0.f;
      #pragma unroll
      for (int q = 0; q < 8; ++q) {
        float4 zv = a4[q];
        d0 = fmaf(cb[(size_t)(q * 4 + 0) * 64], zv.x, d0);
        e0 = fmaf(cw[(size_t)(q * 4 + 0) * 64], zv.x, e0);
        d1 = fmaf(cb[(size_t)(q * 4 + 1) * 64], zv.y, d1);
        e1 = fmaf(cw[(size_t)(q * 4 + 1) * 64], zv.y, e1);
        d0 = fmaf(cb[(size_t)(q * 4 + 2) * 64], zv.z, d0);
        e0 = fmaf(cw[(size_t)(q * 4 + 2) * 64], zv.z, e0);
        d1 = fmaf(cb[(size_t)(q * 4 + 3) * 64], zv.w, d1);
        e1 = fmaf(cw[(size_t)(q * 4 + 3) * 64], zv.w, e1);
      }
      partr[ch * 64 + c] = d0 + d1;
      parti[ch * 64 + c] = e0 + e1;
    }
    __syncthreads();
    // ---- VQ syn select (wave 0)
    if (tid < 64) {
      float dot = 0.f, e = p.ctxsyn_b[l];
      #pragma unroll
      for (int ch = 0; ch < 8; ++ch) {
        dot += partr[ch * 64 + l];
        e += parti[ch * 64 + l];
      }
      float d = p.cnrm_syn[l] - 2.f * dot;
      float m = e;
      #pragma unroll
      for (int mm = 32; mm; mm >>= 1) m = fmaxf(m, __shfl_xor(m, mm));
      float ex = expf(e - m);
      float s = waveAllSum(ex);
      const int pidx = icb[0];
      float score = d - p.gbsig_syn[(size_t)pidx * 64 + l] - CG_C * (ex / s);
      float bv = score; int bi = l;
      #pragma unroll
      for (int mm = 32; mm; mm >>= 1) {
        float ov = __shfl_xor(bv, mm); int oi = __shfl_xor(bi, mm);
        if (ov < bv || (ov == bv && oi < bi)) { bv = ov; bi = oi; }
      }
      if (l == 0) icb[0] = bi;
    }
    __syncthreads();
    // ---- zq_syn gather + VQ sem dots (4 chunks x 64 k)
    if (tid < D2) {
      const int idx = icb[0];
      float zqv = p.cb_syn[(size_t)idx * D2 + tid];
      float df = zqv - acc2[tid];
      lossAcc += df * df;
      zqs[tid] = zqv;
    }
    {
      const int c = tid & 127, ch = tid >> 7;
      const int kb = ch * 64;
      const float* cb = p.cbT_sem + (size_t)kb * 128 + c;
      const float* cw = p.ctxsem_W + (size_t)kb * 128 + c;
      const float4* a4 = (const float4*)(&sl2[kb]);
      float d0 = 0.f, d1 = 0.f, e0 = 0.f, e1 = 0.f;
      #pragma unroll
      for (int q = 0; q < 16; ++q) {
        float4 zv = a4[q];
        d0 = fmaf(cb[(size_t)(q * 4 + 0) * 128], zv.x, d0);
        e0 = fmaf(cw[(size_t)(q * 4 + 0) * 128], zv.x, e0);
        d1 = fmaf(cb[(size_t)(q * 4 + 1) * 128], zv.y, d1);
        e1 = fmaf(cw[(size_t)(q * 4 + 1) * 128], zv.y, e1);
        d0 = fmaf(cb[(size_t)(q * 4 + 2) * 128], zv.z, d0);
        e0 = fmaf(cw[(size_t)(q * 4 + 2) * 128], zv.z, e0);
        d1 = fmaf(cb[(size_t)(q * 4 + 3) * 128], zv.w, d1);
        e1 = fmaf(cw[(size_t)(q * 4 + 3) * 128], zv.w, e1);
      }
      partr[ch * 128 + c] = d0 + d1;
      parti[ch * 128 + c] = e0 + e1;
    }
    __syncthreads();
    // ---- VQ sem select (wave 0)
    if (tid < 64) {
      float dot0 = 0.f, e0 = p.ctxsem_b[l];
      float dot1 = 0.f, e1 = p.ctxsem_b[l + 64];
      #pragma unroll
      for (int ch = 0; ch < 4; ++ch) {
        dot0 += partr[ch * 128 + l];       e0 += parti[ch * 128 + l];
        dot1 += partr[ch * 128 + l + 64];  e1 += parti[ch * 128 + l + 64];
      }
      float d0 = p.cnrm_sem[l] - 2.f * dot0;
      float d1 = p.cnrm_sem[l + 64] - 2.f * dot1;
      float m = fmaxf(e0, e1);
      #pragma unroll
      for (int mm = 32; mm; mm >>= 1) m = fmaxf(m, __shfl_xor(m, mm));
      float x0 = expf(e0 - m), x1 = expf(e1 - m);
      float s = waveAllSum(x0 + x1);
      const int pidx = icb[1];
      float s0 = d0 - p.gbsig_sem[(size_t)pidx * 128 + l] - CG_C * (x0 / s);
      float s1 = d1 - p.gbsig_sem[(size_t)pidx * 128 + l + 64] - CG_C * (x1 / s);
      float bv = s0; int bi = l;
      if (s1 < bv) { bv = s1; bi = l + 64; }
      #pragma unroll
      for (int mm = 32; mm; mm >>= 1) {
        float ov = __shfl_xor(bv, mm); int oi = __shfl_xor(bi, mm);
        if (ov < bv || (ov == bv && oi < bi)) { bv = ov; bi = oi; }
      }
      if (l == 0) icb[1] = bi;
    }
    __syncthreads();
    // ---- zq_sem gather + loss + X write
    if (tid < D2) {
      const int idx = icb[1];
      float zqv = p.cb_sem[(size_t)idx * D2 + tid];
      float df = zqv - sl2[tid];
      lossAcc += df * df;
      p.X[(size_t)(b * SEQ + t) * D2 + tid] = 0.5f * (zqs[tid] + zqv);
    }
    __syncthreads();
  }  // t

  // ---- block loss reduction
  partr[tid] = lossAcc;
  __syncthreads();
  if (tid < 256) partr[tid] += partr[tid + 256];
  __syncthreads();
  if (tid < 128) partr[tid] += partr[tid + 128];
  __syncthreads();
  if (tid < 64) {
    float v = partr[tid] + partr[tid + 64];
    v = waveAllSum(v);
    if (tid == 0) p.lossp[b] = v;
  }
}

// VO = V (complex) @ O (complex)
__global__ __launch_bounds__(256) void voprod_kernel(const float* __restrict__ vr,
                                                     const float* __restrict__ vi,
                                                     const float* __restrict__ orr,
                                                     const float* __restrict__ oii,
                                                     float* __restrict__ VOr,
                                                     float* __restrict__ VOi) {
  __shared__ float a_r[D], a_i[D];
  const int k = blockIdx.x;
  const int tid = threadIdx.x;
  if (tid < D) { a_r[tid] = vr[k * D + tid]; a_i[tid] = vi[k * D + tid]; }
  __syncthreads();
  const int m = tid & 127;
  const int half = tid >> 7;
  float acc = 0.f;
  if (half == 0) {
    #pragma unroll 8
    for (int jj = 0; jj < D; ++jj)
      acc += a_r[jj] * orr[jj * D + m] - a_i[jj] * oii[jj * D + m];
    VOr[k * D + m] = acc;
  } else {
    #pragma unroll 8
    for (int jj = 0; jj < D; ++jj)
      acc += a_r[jj] * oii[jj * D + m] + a_i[jj] * orr[jj * D + m];
    VOi[k * D + m] = acc;
  }
}

__global__ void vqprep_kernel(const float* __restrict__ cb_syn,
                              const float* __restrict__ cb_sem,
                              const float* __restrict__ adj_syn,
                              const float* __restrict__ adj_sem,
                              const float* __restrict__ gate_W,
                              float* __restrict__ cbT_syn,
                              float* __restrict__ cbT_sem,
                              float* __restrict__ cnrm_syn,
                              float* __restrict__ cnrm_sem,
                              float* __restrict__ gbsig_syn,
                              float* __restrict__ gbsig_sem,
                              __half2* __restrict__ gateH) {
  const int tid = blockIdx.x * 256 + threadIdx.x;
  const int nt = gridDim.x * 256;
  for (int e = tid; e < NSYN * D2; e += nt) {
    int c = e / D2, k = e % D2;
    cbT_syn[k * NSYN + c] = cb_syn[e];
  }
  for (int e = tid; e < NSEM * D2; e += nt) {
    int c = e / D2, k = e % D2;
    cbT_sem[k * NSEM + c] = cb_sem[e];
  }
  for (int c = tid; c < NSYN; c += nt) {
    float s = 0.f;
    for (int k = 0; k < D2; ++k) { float v = cb_syn[c * D2 + k]; s += v * v; }
    cnrm_syn[c] = s;
  }
  for (int c = tid; c < NSEM; c += nt) {
    float s = 0.f;
    for (int k = 0; k < D2; ++k) { float v = cb_sem[c * D2 + k]; s += v * v; }
    cnrm_sem[c] = s;
  }
  for (int e = tid; e < NSYN * NSYN; e += nt)
    gbsig_syn[e] = GB_C / (1.f + expf(-adj_syn[e]));
  for (int e = tid; e < NSEM * NSEM; e += nt)
    gbsig_sem[e] = GB_C / (1.f + expf(-adj_sem[e]));
  // gate_W (512 x 128) -> f16 row-pair packed [256][128]
  for (int e = tid; e < 256 * D; e += nt) {
    int r2 = e / D, jj = e % D;
    float w0 = gate_W[(size_t)(2 * r2) * D + jj];
    float w1 = gate_W[(size_t)(2 * r2 + 1) * D + jj];
    gateH[e] = __halves2half2(__float2half(w0), __float2half(w1));
  }
}

// logits = X @ dec_W + dec_b
__global__ __launch_bounds__(256) void dec_kernel(const float* __restrict__ X,
                                                  const float* __restrict__ W,
                                                  const float* __restrict__ bias,
                                                  float* __restrict__ out) {
  __shared__ float A[32][D2];
  const int tid = threadIdx.x;
  const int bx = blockIdx.x;
  const int by = blockIdx.y;
  const float* xr = X + (size_t)by * 32 * D2;
  #pragma unroll
  for (int s = 0; s < 32; ++s) A[s][tid] = xr[s * D2 + tid];
  __syncthreads();
  const int ty = tid >> 5, tx = tid & 31;
  const int col0 = bx * 128 + tx * 4;
  const int r0 = ty * 4;
  float acc[4][4];
  #pragma unroll
  for (int r = 0; r < 4; ++r) {
    acc[r][0] = 0.f; acc[r][1] = 0.f; acc[r][2] = 0.f; acc[r][3] = 0.f;
  }
  const float* wp = W + col0;
  for (int k = 0; k < D2; k += 4) {
    float4 w0 = *(const float4*)(wp + (size_t)(k + 0) * VOC);
    float4 w1 = *(const float4*)(wp + (size_t)(k + 1) * VOC);
    float4 w2 = *(const float4*)(wp + (size_t)(k + 2) * VOC);
    float4 w3 = *(const float4*)(wp + (size_t)(k + 3) * VOC);
    #pragma unroll
    for (int r = 0; r < 4; ++r) {
      float4 a = *(const float4*)&A[r0 + r][k];
      acc[r][0] += a.x * w0.x + a.y * w1.x + a.z * w2.x + a.w * w3.x;
      acc[r][1] += a.x * w0.y + a.y * w1.y + a.z * w2.y + a.w * w3.y;
      acc[r][2] += a.x * w0.z + a.y * w1.z + a.z * w2.z + a.w * w3.z;
      acc[r][3] += a.x * w0.w + a.y * w1.w + a.z * w2.w + a.w * w3.w;
    }
  }
  float4 bv = *(const float4*)(bias + col0);
  #pragma unroll
  for (int r = 0; r < 4; ++r) {
    float4 o;
    o.x = acc[r][0] + bv.x; o.y = acc[r][1] + bv.y;
    o.z = acc[r][2] + bv.z; o.w = acc[r][3] + bv.w;
    *(float4*)(out + (size_t)(by * 32 + r0 + r) * VOC + col0) = o;
  }
}

__global__ void loss_kernel(const float* __restrict__ lp, float* __restrict__ out) {
  int l = threadIdx.x;
  float v = (l < BATCH) ? lp[l] : 0.f;
  #pragma unroll
  for (int off = 32; off; off >>= 1) v += __shfl_down(v, off);
  if (l == 0) out[0] = v * (1.25f / 8192.f);
}

extern "C" void kernel_launch(void* const* d_in, const int* in_sizes, int n_in,
                              void* d_out, int out_size, void* d_ws,
                              size_t ws_size, hipStream_t stream) {
  float* ws = (float*)d_ws;
  float* X = ws;                      // 1048576
  float* lossp = X + 1048576;         // 64
  float* VOr = lossp + 64;            // 16384
  float* VOi = VOr + 16384;           // 16384
  float* cbT_syn = VOi + 16384;       // 16384
  float* cbT_sem = cbT_syn + 16384;   // 32768
  float* cnrm_syn = cbT_sem + 32768;  // 64
  float* cnrm_sem = cnrm_syn + 64;    // 128
  float* gbsig_syn = cnrm_sem + 128;  // 4096
  float* gbsig_sem = gbsig_syn + 4096;// 16384
  __half2* gateH = (__half2*)(gbsig_sem + 16384);  // 32768 u32

  RParams p;
  p.input_ids  = (const int*)d_in[0];
  p.prev_syn   = (const int*)d_in[1];
  p.prev_sem   = (const int*)d_in[2];
  p.emb_mag    = (const float*)d_in[3];
  p.emb_phase  = (const float*)d_in[4];
  p.cell_Wr    = (const float*)d_in[5];
  p.cell_Wi    = (const float*)d_in[6];
  p.norm_scale = (const float*)d_in[7];
  p.norm_shift = (const float*)d_in[8];
  p.modrelu_b  = (const float*)d_in[9];
  p.VOr        = VOr;
  p.VOi        = VOi;
  p.halt_W     = (const float*)d_in[18];
  p.halt_b     = (const float*)d_in[19];
  p.stk_W      = (const float*)d_in[20];
  p.stk_b      = (const float*)d_in[21];
  p.cb_syn     = (const float*)d_in[22];
  p.cb_sem     = (const float*)d_in[23];
  p.ctxsyn_W   = (const float*)d_in[24];
  p.ctxsyn_b   = (const float*)d_in[25];
  p.ctxsem_W   = (const float*)d_in[26];
  p.ctxsem_b   = (const float*)d_in[27];
  p.gate_b     = (const float*)d_in[31];
  p.gateH      = gateH;
  const float* gate_W = (const float*)d_in[30];
  const float* dec_W = (const float*)d_in[32];
  const float* dec_b = (const float*)d_in[33];
  p.cbT_syn = cbT_syn;
  p.cbT_sem = cbT_sem;
  p.cnrm_syn = cnrm_syn;
  p.cnrm_sem = cnrm_sem;
  p.gbsig_syn = gbsig_syn;
  p.gbsig_sem = gbsig_sem;
  p.X = X;
  p.lossp = lossp;

  float* out = (float*)d_out;

  voprod_kernel<<<D, 256, 0, stream>>>((const float*)d_in[14], (const float*)d_in[15],
                                       (const float*)d_in[16], (const float*)d_in[17],
                                       VOr, VOi);
  vqprep_kernel<<<64, 256, 0, stream>>>((const float*)d_in[22], (const float*)d_in[23],
                                        (const float*)d_in[28], (const float*)d_in[29],
                                        gate_W, cbT_syn, cbT_sem, cnrm_syn,
                                        cnrm_sem, gbsig_syn, gbsig_sem, gateH);
  recur_kernel<<<BATCH, 512, 0, stream>>>(p);
  dec_kernel<<<dim3(VOC / 128, BATCH * SEQ / 32), 256, 0, stream>>>(X, dec_W,
                                                                    dec_b, out);
  loss_kernel<<<1, 64, 0, stream>>>(lossp, out + (size_t)BATCH * SEQ * VOC);
}

// Round 10
// 15457.802 us; speedup vs baseline: 1.1771x; 1.1583x over previous
//
#include <hip/hip_runtime.h>
#include <hip/hip_fp16.h>
#include <math.h>

#define D 128
#define D2 256
#define STK 48
#define SEQ 128
#define BATCH 32
#define RDPT 12
#define NSYN 64
#define NSEM 128
#define VOC 16384
#define EPSF 1e-6f
#define GB_C 0.8f
#define CG_C 2.0f

struct RParams {
  const int* input_ids;
  const int* prev_syn;
  const int* prev_sem;
  const float* emb_mag;
  const float* emb_phase;
  const float* cell_Wr;
  const float* cell_Wi;
  const float* norm_scale;
  const float* norm_shift;
  const float* modrelu_b;
  const float* VOr;
  const float* VOi;
  const float* halt_W;
  const float* halt_b;
  const float* stk_W;
  const float* stk_b;
  const float* cb_syn;
  const float* cb_sem;
  const float* ctxsyn_W;
  const float* ctxsyn_b;
  const float* ctxsem_W;
  const float* ctxsem_b;
  const float* gate_b;
  const uint4* gatePk;    // f16-packed gate: [64 octs][128 cols], oct o = rows 8o..8o+7
  const float* cbT_syn;   // [256][64]
  const float* cbT_sem;   // [256][128]
  const float* cnrm_syn;  // [64]
  const float* cnrm_sem;  // [128]
  const float* gbsig_syn; // [64][64]
  const float* gbsig_sem; // [128][128]
  float* X;
  float* lossp;
};

__device__ __forceinline__ float waveAllSum(float v) {
  #pragma unroll
  for (int m = 32; m; m >>= 1) v += __shfl_xor(v, m);
  return v;
}

// Register budget discipline (R2-R9 lesson): unified VGPR+AGPR file gives
// ~256 regs/thread at 2 waves/SIMD; persistent state must stay <= ~190
// (R2's proven level) or the overflow goes to SCRATCH (R6-R9: 52MB/dispatch
// writeback). Here: cell 64 + VO 64 + memv 24 + working ~45 ≈ 195.
__global__ __launch_bounds__(512, 2) void recur_kernel(RParams p) {
  __shared__ uint4 gateLds[64 * D];          // f16-packed gate_W, 128KB
  __shared__ float partr[512], parti[512];
  __shared__ alignas(16) float xr_[D], xi_[D], cr_[D], ci_[D];
  __shared__ float rAiA[D2], marr[D];
  __shared__ alignas(16) float zfc[D2], rd_[D2];
  __shared__ alignas(16) float acc2[D2], sl2[D2];
  __shared__ float zqs[D2];
  __shared__ float sptr[STK];
  __shared__ alignas(16) float nptrs[STK], wms[STK];
  __shared__ float hW_s[D2];
  __shared__ float stW_s[D2 * 3];
  __shared__ float scal[16];
  __shared__ int icb[2];
  __shared__ int ids[SEQ];

  const int tid = threadIdx.x;
  const int b = blockIdx.x;
  const int wv = tid >> 6;
  const int l = tid & 63;
  const int j = tid & 127;
  const int kq = tid >> 7;
  const int k0 = kq * 32;

  // ---- persistent cell + VO weights in registers (128 total)
  float cwr[32], cwi[32], owr[32], owi[32];
  #pragma unroll
  for (int kk = 0; kk < 32; ++kk) {
    cwr[kk] = p.cell_Wr[(size_t)(k0 + kk) * D + j];
    cwi[kk] = p.cell_Wi[(size_t)(k0 + kk) * D + j];
    owr[kk] = p.VOr[(size_t)(k0 + kk) * D + j];
    owi[kk] = p.VOi[(size_t)(k0 + kk) * D + j];
  }
  // ---- packed gate -> LDS (coalesced linear copy, 16 uint4/thread)
  for (int e = tid; e < 64 * D; e += 512) gateLds[e] = p.gatePk[e];
  // ---- per-thread params in regs (tid<128)
  float snsR = 0.f, nshR = 0.f, smbR = 0.f, sgbR = 0.f;
  if (tid < D) {
    snsR = p.norm_scale[tid];
    nshR = p.norm_shift[tid];
    smbR = p.modrelu_b[tid];
    sgbR = p.gate_b[tid];
  }
  if (tid < D2) hW_s[tid] = p.halt_W[tid];
  for (int e = tid; e < D2 * 3; e += 512) stW_s[e] = p.stk_W[e];
  if (tid < SEQ) ids[tid] = p.input_ids[(size_t)b * SEQ + tid];
  if (tid < STK) sptr[tid] = (tid == 0) ? 1.f : 0.f;
  if (tid == 0) { icb[0] = p.prev_syn[b]; icb[1] = p.prev_sem[b]; }
  const float hb = p.halt_b[0];
  const float sb0 = p.stk_b[0], sb1 = p.stk_b[1], sb2 = p.stk_b[2];

  // stack memory in regs: (mdl = tid&255, mjh = tid>>8) rows mjh*24..+23
  float memv[24];
  #pragma unroll
  for (int q = 0; q < 24; ++q) memv[q] = 0.f;
  const int mdl = tid & 255, mjh = tid >> 8;
  float lossAcc = 0.f;
  float remv = 1.f;
  float mNxt = 0.f, pNxt = 0.f;
  __syncthreads();

  if (tid < D) {
    const int id0 = ids[0];
    mNxt = p.emb_mag[(size_t)id0 * D + tid];
    pNxt = p.emb_phase[(size_t)id0 * D + tid];
  }

  for (int t = 0; t < SEQ; ++t) {
    if (tid < D) {
      float sv, cv;
      sincosf(pNxt, &sv, &cv);
      xr_[tid] = mNxt * cv;
      xi_[tid] = mNxt * sv;
    }
    float accR = 0.f, accI = 0.f, slR = 0.f, slI = 0.f;
    if (tid < 64) remv = 1.f;
    __syncthreads();

    for (int n = 0; n < RDPT; ++n) {
      // ---- P1: cell clin partials (reg weights, float4 broadcast x)
      {
        const float4* x4r = (const float4*)(&xr_[k0]);
        const float4* x4i = (const float4*)(&xi_[k0]);
        float a0 = 0.f, a1 = 0.f, a2 = 0.f, a3 = 0.f;
        #pragma unroll
        for (int q = 0; q < 8; ++q) {
          float4 xa = x4r[q];
          float4 xb = x4i[q];
          a0 = fmaf(xa.x, cwr[q*4+0], a0); a0 = fmaf(-xb.x, cwi[q*4+0], a0);
          a1 = fmaf(xb.x, cwr[q*4+0], a1); a1 = fmaf(xa.x, cwi[q*4+0], a1);
          a2 = fmaf(xa.y, cwr[q*4+1], a2); a2 = fmaf(-xb.y, cwi[q*4+1], a2);
          a3 = fmaf(xb.y, cwr[q*4+1], a3); a3 = fmaf(xa.y, cwi[q*4+1], a3);
          a0 = fmaf(xa.z, cwr[q*4+2], a0); a0 = fmaf(-xb.z, cwi[q*4+2], a0);
          a1 = fmaf(xb.z, cwr[q*4+2], a1); a1 = fmaf(xa.z, cwi[q*4+2], a1);
          a2 = fmaf(xa.w, cwr[q*4+3], a2); a2 = fmaf(-xb.w, cwi[q*4+3], a2);
          a3 = fmaf(xb.w, cwr[q*4+3], a3); a3 = fmaf(xa.w, cwi[q*4+3], a3);
        }
        partr[tid] = a0 + a2;
        parti[tid] = a1 + a3;
      }
      __syncthreads();
      // ---- P2: combine + magnitude (128 threads)
      if (tid < D) {
        float rr = partr[tid] + partr[tid + 128] + partr[tid + 256] + partr[tid + 384];
        float ii = parti[tid] + parti[tid + 128] + parti[tid + 256] + parti[tid + 384];
        rAiA[tid] = rr;
        rAiA[tid + 128] = ii;
        marr[tid] = sqrtf(rr * rr + ii * ii) + EPSF;
      }
      __syncthreads();
      // ---- P3: mean/var (wave 0)
      if (tid < 64) {
        float m0 = marr[l], m1 = marr[l + 64];
        float mean = waveAllSum(m0 + m1) * (1.f / D);
        float d0 = m0 - mean, d1 = m1 - mean;
        float v = waveAllSum(d0 * d0 + d1 * d1);
        if (l == 0) {
          scal[1] = mean;
          scal[2] = rsqrtf(v * (1.f / (D - 1)) + EPSF);
        }
      }
      __syncthreads();
      // ---- P4: norm + modReLU (128 threads, reg params)
      if (tid < D) {
        float m = marr[tid];
        float nm = (m - scal[1]) * scal[2] * snsR + nshR;
        float r_ = nm * rAiA[tid] / m;
        float i_ = nm * rAiA[tid + 128] / m;
        float nn = sqrtf(r_ * r_ + i_ * i_) + EPSF;
        float sc = fmaxf(nn + smbR, 0.f) / nn;
        cr_[tid] = r_ * sc;
        ci_[tid] = i_ * sc;
      }
      __syncthreads();
      // ---- P5: fused v@o clin (reg weights)
      {
        const float4* c4r = (const float4*)(&cr_[k0]);
        const float4* c4i = (const float4*)(&ci_[k0]);
        float a0 = 0.f, a1 = 0.f, a2 = 0.f, a3 = 0.f;
        #pragma unroll
        for (int q = 0; q < 8; ++q) {
          float4 xa = c4r[q];
          float4 xb = c4i[q];
          a0 = fmaf(xa.x, owr[q*4+0], a0); a0 = fmaf(-xb.x, owi[q*4+0], a0);
          a1 = fmaf(xb.x, owr[q*4+0], a1); a1 = fmaf(xa.x, owi[q*4+0], a1);
          a2 = fmaf(xa.y, owr[q*4+1], a2); a2 = fmaf(-xb.y, owi[q*4+1], a2);
          a3 = fmaf(xb.y, owr[q*4+1], a3); a3 = fmaf(xa.y, owi[q*4+1], a3);
          a0 = fmaf(xa.z, owr[q*4+2], a0); a0 = fmaf(-xb.z, owi[q*4+2], a0);
          a1 = fmaf(xb.z, owr[q*4+2], a1); a1 = fmaf(xa.z, owi[q*4+2], a1);
          a2 = fmaf(xa.w, owr[q*4+3], a2); a2 = fmaf(-xb.w, owi[q*4+3], a2);
          a3 = fmaf(xb.w, owr[q*4+3], a3); a3 = fmaf(xa.w, owi[q*4+3], a3);
        }
        partr[tid] = a0 + a2;
        parti[tid] = a1 + a3;
      }
      __syncthreads();
      // ---- P6: combine -> zfc (256 threads)
      if (tid < 256) {
        if (tid < 128) {
          zfc[tid] = partr[tid] + partr[tid + 128] + partr[tid + 256] + partr[tid + 384];
        } else {
          const int d = tid - 128;
          zfc[tid] = parti[d] + parti[d + 128] + parti[d + 256] + parti[d + 384];
        }
      }
      __syncthreads();
      // ---- P7: head dots in parallel (waves 0-3)
      if (tid < 256) {
        float z0 = zfc[l], z1 = zfc[l + 64], z2 = zfc[l + 128], z3 = zfc[l + 192];
        float s;
        if (wv == 0) {
          s = z0 * hW_s[l] + z1 * hW_s[l + 64] + z2 * hW_s[l + 128] + z3 * hW_s[l + 192];
        } else {
          const int c = wv - 1;
          s = z0 * stW_s[l * 3 + c] + z1 * stW_s[(l + 64) * 3 + c] +
              z2 * stW_s[(l + 128) * 3 + c] + z3 * stW_s[(l + 192) * 3 + c];
        }
        s = waveAllSum(s);
        if (l == 0) scal[4 + wv] = s;
      }
      __syncthreads();
      // ---- P8: wave0: softmax + halt + stack pointer
      if (tid < 64) {
        float halt = 1.f / (1.f + expf(-(scal[4] + hb)));
        float e0 = scal[5] + sb0, e1 = scal[6] + sb1, e2 = scal[7] + sb2;
        float mx = fmaxf(e0, fmaxf(e1, e2));
        float x0 = expf(e0 - mx), x1 = expf(e1 - mx), x2 = expf(e2 - mx);
        float sm = x0 + x1 + x2;
        float push = x0 / sm, pop = x1 / sm, noop = x2 / sm;
        float wgt = (n == RDPT - 1) ? remv : remv * halt;
        if (l == 0) scal[3] = wgt;
        remv = remv * (1.f - halt);
        float pj = 0.f, pu = 0.f, pd = 0.f;
        if (l < STK) {
          pj = sptr[l];
          pu = sptr[(l + STK - 1) % STK];
          pd = sptr[(l + 1) % STK];
        }
        float np_ = push * pu + pop * pd + noop * pj;
        float wm_ = push * pu;
        float ssum = waveAllSum((l < STK) ? np_ : 0.f);
        float inv = 1.f / (ssum + EPSF);
        if (l < STK) {
          np_ *= inv;
          nptrs[l] = np_;
          sptr[l] = np_;
          wms[l] = wm_;
        }
      }
      __syncthreads();
      // ---- P9: stack mem update + read partials (float4 broadcasts)
      {
        const float4* wm4 = (const float4*)wms;
        const float4* np4 = (const float4*)nptrs;
        float zfd = zfc[mdl];
        float accA = 0.f, accB = 0.f;
        #pragma unroll
        for (int m4 = 0; m4 < 6; ++m4) {
          float4 wmv = wm4[mjh * 6 + m4];
          float4 npv = np4[mjh * 6 + m4];
          const int base = m4 * 4;
          memv[base + 0] = wmv.x * zfd + memv[base + 0] * (1.f - wmv.x);
          accA = fmaf(memv[base + 0], npv.x, accA);
          memv[base + 1] = wmv.y * zfd + memv[base + 1] * (1.f - wmv.y);
          accB = fmaf(memv[base + 1], npv.y, accB);
          memv[base + 2] = wmv.z * zfd + memv[base + 2] * (1.f - wmv.z);
          accA = fmaf(memv[base + 2], npv.z, accA);
          memv[base + 3] = wmv.w * zfd + memv[base + 3] * (1.f - wmv.w);
          accB = fmaf(memv[base + 3], npv.w, accB);
        }
        partr[tid] = accA + accB;
      }
      __syncthreads();
      // ---- P10: rd combine
      if (tid < D2) rd_[tid] = partr[tid] + partr[tid + 256];
      __syncthreads();
      // ---- P11: gate partials (f16 gate from LDS, float4 broadcast src)
      {
        const float4* s4 = (kq < 2) ? (const float4*)(&zfc[kq * 128])
                                    : (const float4*)(&rd_[(kq - 2) * 128]);
        const uint4* g16 = &gateLds[(kq * 16) * D + j];
        float g0 = 0.f, g1 = 0.f, g2 = 0.f, g3 = 0.f;
        #pragma unroll
        for (int o = 0; o < 16; ++o) {
          float4 xa = s4[2 * o];
          float4 xb = s4[2 * o + 1];
          uint4 w = g16[(size_t)o * D];
          union { unsigned u; __half2 h; } c0, c1, c2, c3;
          c0.u = w.x; c1.u = w.y; c2.u = w.z; c3.u = w.w;
          float2 f0 = __half22float2(c0.h);
          float2 f1 = __half22float2(c1.h);
          float2 f2 = __half22float2(c2.h);
          float2 f3 = __half22float2(c3.h);
          g0 = fmaf(xa.x, f0.x, g0); g1 = fmaf(xa.y, f0.y, g1);
          g2 = fmaf(xa.z, f1.x, g2); g3 = fmaf(xa.w, f1.y, g3);
          g0 = fmaf(xb.x, f2.x, g0); g1 = fmaf(xb.y, f2.y, g1);
          g2 = fmaf(xb.z, f3.x, g2); g3 = fmaf(xb.w, f3.y, g3);
        }
        partr[tid] = (g0 + g1) + (g2 + g3);
      }
      __syncthreads();
      // ---- P12: sigmoid gate + gated residual + reg accumulators
      if (tid < D) {
        float g = partr[tid] + partr[tid + 128] + partr[tid + 256] +
                  partr[tid + 384] + sgbR;
        g = 1.f / (1.f + expf(-g));
        float pr_ = zfc[tid], pi_ = zfc[tid + 128];
        float rr_ = rd_[tid], ri_ = rd_[tid + 128];
        float nzr = (1.f - g) * pr_ + g * pi_ + g * (rr_ - ri_);
        float nzi = (1.f - g) * pi_ - g * pr_ + g * (ri_ + rr_);
        xr_[tid] = nzr;
        xi_[tid] = nzi;
        float wgt = scal[3];
        accR += wgt * nzr;
        accI += wgt * nzi;
        slR += nzr * (1.f / RDPT);
        slI += nzi * (1.f / RDPT);
      }
      __syncthreads();
    }  // n

    // ---- emb prefetch for t+1 (overlaps VQ section)
    if (tid < D) {
      const int idn = ids[(t + 1 < SEQ) ? t + 1 : t];
      mNxt = p.emb_mag[(size_t)idn * D + tid];
      pNxt = p.emb_phase[(size_t)idn * D + tid];
    }
    // ---- flush accumulators to LDS
    if (tid < D) {
      acc2[tid] = accR; acc2[tid + 128] = accI;
      sl2[tid] = slR;  sl2[tid + 128] = slI;
    }
    __syncthreads();

    // ---- VQ syn dots: 8 chunks x 32 k (float4 broadcast src)
    {
      const int c = tid & 63, ch = tid >> 6;
      const int kb = ch * 32;
      const float* cb = p.cbT_syn + (size_t)kb * 64 + c;
      const float* cw = p.ctxsyn_W + (size_t)kb * 64 + c;
      const float4* a4 = (const float4*)(&acc2[kb]);
      float d0 = 0.f, d1 = 0.f, e0 = 0.f, e1 = 0.f;
      #pragma unroll
      for (int q = 0; q < 8; ++q) {
        float4 zv = a4[q];
        d0 = fmaf(cb[(size_t)(q * 4 + 0) * 64], zv.x, d0);
        e0 = fmaf(cw[(size_t)(q * 4 + 0) * 64], zv.x, e0);
        d1 = fmaf(cb[(size_t)(q * 4 + 1) * 64], zv.y, d1);
        e1 = fmaf(cw[(size_t)(q * 4 + 1) * 64], zv.y, e1);
        d0 = fmaf(cb[(size_t)(q * 4 + 2) * 64], zv.z, d0);
        e0 = fmaf(cw[(size_t)(q * 4 + 2) * 64], zv.z, e0);
        d1 = fmaf(cb[(size_t)(q * 4 + 3) * 64], zv.w, d1);
        e1 = fmaf(cw[(size_t)(q * 4 + 3) * 64], zv.w, e1);
      }
      partr[ch * 64 + c] = d0 + d1;
      parti[ch * 64 + c] = e0 + e1;
    }
    __syncthreads();
    // ---- VQ syn select (wave 0)
    if (tid < 64) {
      float dot = 0.f, e = p.ctxsyn_b[l];
      #pragma unroll
      for (int ch = 0; ch < 8; ++ch) {
        dot += partr[ch * 64 + l];
        e += parti[ch * 64 + l];
      }
      float d = p.cnrm_syn[l] - 2.f * dot;
      float m = e;
      #pragma unroll
      for (int mm = 32; mm; mm >>= 1) m = fmaxf(m, __shfl_xor(m, mm));
      float ex = expf(e - m);
      float s = waveAllSum(ex);
      const int pidx = icb[0];
      float score = d - p.gbsig_syn[(size_t)pidx * 64 + l] - CG_C * (ex / s);
      float bv = score; int bi = l;
      #pragma unroll
      for (int mm = 32; mm; mm >>= 1) {
        float ov = __shfl_xor(bv, mm); int oi = __shfl_xor(bi, mm);
        if (ov < bv || (ov == bv && oi < bi)) { bv = ov; bi = oi; }
      }
      if (l == 0) icb[0] = bi;
    }
    __syncthreads();
    // ---- zq_syn gather + VQ sem dots (4 chunks x 64 k)
    if (tid < D2) {
      const int idx = icb[0];
      float zqv = p.cb_syn[(size_t)idx * D2 + tid];
      float df = zqv - acc2[tid];
      lossAcc += df * df;
      zqs[tid] = zqv;
    }
    {
      const int c = tid & 127, ch = tid >> 7;
      const int kb = ch * 64;
      const float* cb = p.cbT_sem + (size_t)kb * 128 + c;
      const float* cw = p.ctxsem_W + (size_t)kb * 128 + c;
      const float4* a4 = (const float4*)(&sl2[kb]);
      float d0 = 0.f, d1 = 0.f, e0 = 0.f, e1 = 0.f;
      #pragma unroll
      for (int q = 0; q < 16; ++q) {
        float4 zv = a4[q];
        d0 = fmaf(cb[(size_t)(q * 4 + 0) * 128], zv.x, d0);
        e0 = fmaf(cw[(size_t)(q * 4 + 0) * 128], zv.x, e0);
        d1 = fmaf(cb[(size_t)(q * 4 + 1) * 128], zv.y, d1);
        e1 = fmaf(cw[(size_t)(q * 4 + 1) * 128], zv.y, e1);
        d0 = fmaf(cb[(size_t)(q * 4 + 2) * 128], zv.z, d0);
        e0 = fmaf(cw[(size_t)(q * 4 + 2) * 128], zv.z, e0);
        d1 = fmaf(cb[(size_t)(q * 4 + 3) * 128], zv.w, d1);
        e1 = fmaf(cw[(size_t)(q * 4 + 3) * 128], zv.w, e1);
      }
      partr[ch * 128 + c] = d0 + d1;
      parti[ch * 128 + c] = e0 + e1;
    }
    __syncthreads();
    // ---- VQ sem select (wave 0)
    if (tid < 64) {
      float dot0 = 0.f, e0 = p.ctxsem_b[l];
      float dot1 = 0.f, e1 = p.ctxsem_b[l + 64];
      #pragma unroll
      for (int ch = 0; ch < 4; ++ch) {
        dot0 += partr[ch * 128 + l];       e0 += parti[ch * 128 + l];
        dot1 += partr[ch * 128 + l + 64];  e1 += parti[ch * 128 + l + 64];
      }
      float d0 = p.cnrm_sem[l] - 2.f * dot0;
      float d1 = p.cnrm_sem[l + 64] - 2.f * dot1;
      float m = fmaxf(e0, e1);
      #pragma unroll
      for (int mm = 32; mm; mm >>= 1) m = fmaxf(m, __shfl_xor(m, mm));
      float x0 = expf(e0 - m), x1 = expf(e1 - m);
      float s = waveAllSum(x0 + x1);
      const int pidx = icb[1];
      float s0 = d0 - p.gbsig_sem[(size_t)pidx * 128 + l] - CG_C * (x0 / s);
      float s1 = d1 - p.gbsig_sem[(size_t)pidx * 128 + l + 64] - CG_C * (x1 / s);
      float bv = s0; int bi = l;
      if (s1 < bv) { bv = s1; bi = l + 64; }
      #pragma unroll
      for (int mm = 32; mm; mm >>= 1) {
        float ov = __shfl_xor(bv, mm); int oi = __shfl_xor(bi, mm);
        if (ov < bv || (ov == bv && oi < bi)) { bv = ov; bi = oi; }
      }
      if (l == 0) icb[1] = bi;
    }
    __syncthreads();
    // ---- zq_sem gather + loss + X write
    if (tid < D2) {
      const int idx = icb[1];
      float zqv = p.cb_sem[(size_t)idx * D2 + tid];
      float df = zqv - sl2[tid];
      lossAcc += df * df;
      p.X[(size_t)(b * SEQ + t) * D2 + tid] = 0.5f * (zqs[tid] + zqv);
    }
    __syncthreads();
  }  // t

  // ---- block loss reduction
  partr[tid] = lossAcc;
  __syncthreads();
  if (tid < 256) partr[tid] += partr[tid + 256];
  __syncthreads();
  if (tid < 128) partr[tid] += partr[tid + 128];
  __syncthreads();
  if (tid < 64) {
    float v = partr[tid] + partr[tid + 64];
    v = waveAllSum(v);
    if (tid == 0) p.lossp[b] = v;
  }
}

// VO = V (complex) @ O (complex)
__global__ __launch_bounds__(256) void voprod_kernel(const float* __restrict__ vr,
                                                     const float* __restrict__ vi,
                                                     const float* __restrict__ orr,
                                                     const float* __restrict__ oii,
                                                     float* __restrict__ VOr,
                                                     float* __restrict__ VOi) {
  __shared__ float a_r[D], a_i[D];
  const int k = blockIdx.x;
  const int tid = threadIdx.x;
  if (tid < D) { a_r[tid] = vr[k * D + tid]; a_i[tid] = vi[k * D + tid]; }
  __syncthreads();
  const int m = tid & 127;
  const int half = tid >> 7;
  float acc = 0.f;
  if (half == 0) {
    #pragma unroll 8
    for (int jj = 0; jj < D; ++jj)
      acc += a_r[jj] * orr[jj * D + m] - a_i[jj] * oii[jj * D + m];
    VOr[k * D + m] = acc;
  } else {
    #pragma unroll 8
    for (int jj = 0; jj < D; ++jj)
      acc += a_r[jj] * oii[jj * D + m] + a_i[jj] * orr[jj * D + m];
    VOi[k * D + m] = acc;
  }
}

__global__ void vqprep_kernel(const float* __restrict__ cb_syn,
                              const float* __restrict__ cb_sem,
                              const float* __restrict__ adj_syn,
                              const float* __restrict__ adj_sem,
                              const float* __restrict__ gate_W,
                              float* __restrict__ cbT_syn,
                              float* __restrict__ cbT_sem,
                              float* __restrict__ cnrm_syn,
                              float* __restrict__ cnrm_sem,
                              float* __restrict__ gbsig_syn,
                              float* __restrict__ gbsig_sem,
                              uint4* __restrict__ gatePk) {
  const int tid = blockIdx.x * 256 + threadIdx.x;
  const int nt = gridDim.x * 256;
  for (int e = tid; e < NSYN * D2; e += nt) {
    int c = e / D2, k = e % D2;
    cbT_syn[k * NSYN + c] = cb_syn[e];
  }
  for (int e = tid; e < NSEM * D2; e += nt) {
    int c = e / D2, k = e % D2;
    cbT_sem[k * NSEM + c] = cb_sem[e];
  }
  for (int c = tid; c < NSYN; c += nt) {
    float s = 0.f;
    for (int k = 0; k < D2; ++k) { float v = cb_syn[c * D2 + k]; s += v * v; }
    cnrm_syn[c] = s;
  }
  for (int c = tid; c < NSEM; c += nt) {
    float s = 0.f;
    for (int k = 0; k < D2; ++k) { float v = cb_sem[c * D2 + k]; s += v * v; }
    cnrm_sem[c] = s;
  }
  for (int e = tid; e < NSYN * NSYN; e += nt)
    gbsig_syn[e] = GB_C / (1.f + expf(-adj_syn[e]));
  for (int e = tid; e < NSEM * NSEM; e += nt)
    gbsig_sem[e] = GB_C / (1.f + expf(-adj_sem[e]));
  // gate_W (512 x 128) -> f16 oct-packed [64][128]: oct o = rows 8o..8o+7
  for (int e = tid; e < 64 * D; e += nt) {
    int o = e / D, jj = e % D;
    union { unsigned u; __half2 h; } w0, w1, w2, w3;
    w0.h = __halves2half2(__float2half(gate_W[(size_t)(8 * o + 0) * D + jj]),
                          __float2half(gate_W[(size_t)(8 * o + 1) * D + jj]));
    w1.h = __halves2half2(__float2half(gate_W[(size_t)(8 * o + 2) * D + jj]),
                          __float2half(gate_W[(size_t)(8 * o + 3) * D + jj]));
    w2.h = __halves2half2(__float2half(gate_W[(size_t)(8 * o + 4) * D + jj]),
                          __float2half(gate_W[(size_t)(8 * o + 5) * D + jj]));
    w3.h = __halves2half2(__float2half(gate_W[(size_t)(8 * o + 6) * D + jj]),
                          __float2half(gate_W[(size_t)(8 * o + 7) * D + jj]));
    uint4 pk;
    pk.x = w0.u; pk.y = w1.u; pk.z = w2.u; pk.w = w3.u;
    gatePk[e] = pk;
  }
}

// logits = X @ dec_W + dec_b
__global__ __launch_bounds__(256) void dec_kernel(const float* __restrict__ X,
                                                  const float* __restrict__ W,
                                                  const float* __restrict__ bias,
                                                  float* __restrict__ out) {
  __shared__ float A[32][D2];
  const int tid = threadIdx.x;
  const int bx = blockIdx.x;
  const int by = blockIdx.y;
  const float* xr = X + (size_t)by * 32 * D2;
  #pragma unroll
  for (int s = 0; s < 32; ++s) A[s][tid] = xr[s * D2 + tid];
  __syncthreads();
  const int ty = tid >> 5, tx = tid & 31;
  const int col0 = bx * 128 + tx * 4;
  const int r0 = ty * 4;
  float acc[4][4];
  #pragma unroll
  for (int r = 0; r < 4; ++r) {
    acc[r][0] = 0.f; acc[r][1] = 0.f; acc[r][2] = 0.f; acc[r][3] = 0.f;
  }
  const float* wp = W + col0;
  for (int k = 0; k < D2; k += 4) {
    float4 w0 = *(const float4*)(wp + (size_t)(k + 0) * VOC);
    float4 w1 = *(const float4*)(wp + (size_t)(k + 1) * VOC);
    float4 w2 = *(const float4*)(wp + (size_t)(k + 2) * VOC);
    float4 w3 = *(const float4*)(wp + (size_t)(k + 3) * VOC);
    #pragma unroll
    for (int r = 0; r < 4; ++r) {
      float4 a = *(const float4*)&A[r0 + r][k];
      acc[r][0] += a.x * w0.x + a.y * w1.x + a.z * w2.x + a.w * w3.x;
      acc[r][1] += a.x * w0.y + a.y * w1.y + a.z * w2.y + a.w * w3.y;
      acc[r][2] += a.x * w0.z + a.y * w1.z + a.z * w2.z + a.w * w3.z;
      acc[r][3] += a.x * w0.w + a.y * w1.w + a.z * w2.w + a.w * w3.w;
    }
  }
  float4 bv = *(const float4*)(bias + col0);
  #pragma unroll
  for (int r = 0; r < 4; ++r) {
    float4 o;
    o.x = acc[r][0] + bv.x; o.y = acc[r][1] + bv.y;
    o.z = acc[r][2] + bv.z; o.w = acc[r][3] + bv.w;
    *(float4*)(out + (size_t)(by * 32 + r0 + r) * VOC + col0) = o;
  }
}

__global__ void loss_kernel(const float* __restrict__ lp, float* __restrict__ out) {
  int l = threadIdx.x;
  float v = (l < BATCH) ? lp[l] : 0.f;
  #pragma unroll
  for (int off = 32; off; off >>= 1) v += __shfl_down(v, off);
  if (l == 0) out[0] = v * (1.25f / 8192.f);
}

extern "C" void kernel_launch(void* const* d_in, const int* in_sizes, int n_in,
                              void* d_out, int out_size, void* d_ws,
                              size_t ws_size, hipStream_t stream) {
  float* ws = (float*)d_ws;
  float* X = ws;                      // 1048576
  float* lossp = X + 1048576;         // 64
  float* VOr = lossp + 64;            // 16384
  float* VOi = VOr + 16384;           // 16384
  float* cbT_syn = VOi + 16384;       // 16384
  float* cbT_sem = cbT_syn + 16384;   // 32768
  float* cnrm_syn = cbT_sem + 32768;  // 64
  float* cnrm_sem = cnrm_syn + 64;    // 128
  float* gbsig_syn = cnrm_sem + 128;  // 4096
  float* gbsig_sem = gbsig_syn + 4096;// 16384
  uint4* gatePk = (uint4*)(gbsig_sem + 16384);  // 8192 uint4 = 128KB

  RParams p;
  p.input_ids  = (const int*)d_in[0];
  p.prev_syn   = (const int*)d_in[1];
  p.prev_sem   = (const int*)d_in[2];
  p.emb_mag    = (const float*)d_in[3];
  p.emb_phase  = (const float*)d_in[4];
  p.cell_Wr    = (const float*)d_in[5];
  p.cell_Wi    = (const float*)d_in[6];
  p.norm_scale = (const float*)d_in[7];
  p.norm_shift = (const float*)d_in[8];
  p.modrelu_b  = (const float*)d_in[9];
  p.VOr        = VOr;
  p.VOi        = VOi;
  p.halt_W     = (const float*)d_in[18];
  p.halt_b     = (const float*)d_in[19];
  p.stk_W      = (const float*)d_in[20];
  p.stk_b      = (const float*)d_in[21];
  p.cb_syn     = (const float*)d_in[22];
  p.cb_sem     = (const float*)d_in[23];
  p.ctxsyn_W   = (const float*)d_in[24];
  p.ctxsyn_b   = (const float*)d_in[25];
  p.ctxsem_W   = (const float*)d_in[26];
  p.ctxsem_b   = (const float*)d_in[27];
  p.gate_b     = (const float*)d_in[31];
  p.gatePk     = gatePk;
  const float* gate_W = (const float*)d_in[30];
  const float* dec_W = (const float*)d_in[32];
  const float* dec_b = (const float*)d_in[33];
  p.cbT_syn = cbT_syn;
  p.cbT_sem = cbT_sem;
  p.cnrm_syn = cnrm_syn;
  p.cnrm_sem = cnrm_sem;
  p.gbsig_syn = gbsig_syn;
  p.gbsig_sem = gbsig_sem;
  p.X = X;
  p.lossp = lossp;

  float* out = (float*)d_out;

  voprod_kernel<<<D, 256, 0, stream>>>((const float*)d_in[14], (const float*)d_in[15],
                                       (const float*)d_in[16], (const float*)d_in[17],
                                       VOr, VOi);
  vqprep_kernel<<<64, 256, 0, stream>>>((const float*)d_in[22], (const float*)d_in[23],
                                        (const float*)d_in[28], (const float*)d_in[29],
                                        gate_W, cbT_syn, cbT_sem, cnrm_syn,
                                        cnrm_sem, gbsig_syn, gbsig_sem, gatePk);
  recur_kernel<<<BATCH, 512, 0, stream>>>(p);
  dec_kernel<<<dim3(VOC / 128, BATCH * SEQ / 32), 256, 0, stream>>>(X, dec_W,
                                                                    dec_b, out);
  loss_kernel<<<1, 64, 0, stream>>>(lossp, out + (size_t)BATCH * SEQ * VOC);
}